// Round 3
// baseline (119.174 us; speedup 1.0000x reference)
//
#include <hip/hip_runtime.h>

#define TT 20
#define NSTK 1000
#define THREADS 256

typedef float f32x4 __attribute__((ext_vector_type(4)));
typedef short bf16x8 __attribute__((ext_vector_type(8)));

__device__ __forceinline__ short f2bf(float f) {
    unsigned u = __float_as_uint(f);
    return (short)((u + 0x7fffu + ((u >> 16) & 1u)) >> 16);   // RNE
}
__device__ __forceinline__ float bf2f(short h) {
    return __uint_as_float(((unsigned)(unsigned short)h) << 16);
}
__device__ __forceinline__ float rcp_f(float x) { return __builtin_amdgcn_rcpf(x); }
__device__ __forceinline__ float sigmoid_f(float x) { return rcp_f(1.0f + __expf(-x)); }
__device__ __forceinline__ float tanh_f(float x) {
    return 1.0f - 2.0f * rcp_f(__expf(2.0f * x) + 1.0f);
}

// A-frag LDS layout (bf16): [kf 0..3][q=lane>>4 0..3][row 0..15][j 0..7]
//   k = kf*32 + q*8 + j ; rows 0..7 = batches, 8..15 zero padding.
// Same (q,j)->k convention used for A and B frags, so any bijective error in
// the true HW k-mapping cancels in the MFMA dot product.
#define AIDX(kf, q, row, j) ((((kf) * 4 + (q)) * 16 + (row)) * 8 + (j))

extern "C" __global__ void __launch_bounds__(THREADS, 2)
lstm_att_mfma(const float* __restrict__ x,
              const float* __restrict__ Wi, const float* __restrict__ bi,
              const float* __restrict__ Wo, const float* __restrict__ bo,
              const float* __restrict__ Wf, const float* __restrict__ bf_,
              const float* __restrict__ Wc, const float* __restrict__ bc,
              const float* __restrict__ Wt,
              float* __restrict__ out)
{
    __shared__ __align__(16) float wbuf[8192];      // 32 KB: W staging (init only)
    __shared__ __align__(16) short ahi[2048];       // 4 KB: xh hi bf16, frag layout
    __shared__ __align__(16) short alo[2048];       // 4 KB: xh lo bf16
    __shared__ __align__(16) float wtlds[TT * 64];  // 5 KB
    __shared__ __align__(16) float sparts[32];      // cross-wave score partials

    const int n    = blockIdx.x;
    const int tid  = threadIdx.x;
    const int lane = tid & 63;
    const int w    = tid >> 6;                 // wave id 0..3
    const int q    = lane >> 4;                // frag k-group
    const int r16  = lane & 15;                // frag row/col index
    const int dcol = w * 16 + r16;             // this lane's d (0..63)
    const int g4   = (lane >> 4) * 4;          // batch base for C rows (lanes<32)

    // ---------------- init ----------------
    #pragma unroll
    for (int u = 0; u < 8; ++u) { ahi[tid + u * THREADS] = 0; alo[tid + u * THREADS] = 0; }
    #pragma unroll
    for (int u = 0; u < 5; ++u)
        wtlds[tid + u * THREADS] = Wt[(size_t)n * (TT * 64) + tid + u * THREADS];

    // persistent B-fragments: W[k][d] for gate g, cols dcol, hi/lo bf16
    bf16x8 bhi[4][4], blo[4][4];               // [gate][kf]
    {
        const float* Wg[4] = {Wi, Wo, Wf, Wc};
        #pragma unroll
        for (int g = 0; g < 4; ++g) {
            __syncthreads();                   // wbuf reuse guard
            const float4* src = (const float4*)(Wg[g] + (size_t)n * 8192);
            float4* dst = (float4*)wbuf;
            #pragma unroll
            for (int u = 0; u < 8; ++u) dst[tid + u * THREADS] = src[tid + u * THREADS];
            __syncthreads();
            #pragma unroll
            for (int kf = 0; kf < 4; ++kf) {
                #pragma unroll
                for (int j = 0; j < 8; ++j) {
                    const float v = wbuf[(kf * 32 + q * 8 + j) * 64 + dcol];
                    const short hb = f2bf(v);
                    bhi[g][kf][j] = hb;
                    blo[g][kf][j] = f2bf(v - bf2f(hb));
                }
            }
        }
    }
    float biasv[4];
    biasv[0] = bi[n * 64 + dcol];
    biasv[1] = bo[n * 64 + dcol];
    biasv[2] = bf_[n * 64 + dcol];
    biasv[3] = bc[n * 64 + dcol];

    // per-lane state: 4 batches (g4+r) at dim dcol  (valid for lane<32)
    float cst[4]  = {0.f, 0.f, 0.f, 0.f};
    float onum[4] = {0.f, 0.f, 0.f, 0.f};
    float mst[4]  = {-3.0e38f, -3.0e38f, -3.0e38f, -3.0e38f};
    float sst[4]  = {0.f, 0.f, 0.f, 0.f};
    float h[4]    = {0.f, 0.f, 0.f, 0.f};

    __syncthreads();   // h-part of ahi/alo (zeros) visible before first reads

    for (int t = 0; t < TT; ++t) {
        // ---- stage x[b,t,n,:] into frag-layout LDS (hi/lo bf16) ----
        {
            const int sb = tid >> 5, dx = (tid & 31) * 2;
            const float2 xv = *(const float2*)(x + ((size_t)(sb * TT + t) * NSTK + n) * 64 + dx);
            const int kf = dx >> 5, kk = dx & 31, sq = kk >> 3, sj = kk & 7;
            const short h0 = f2bf(xv.x), h1 = f2bf(xv.y);
            const short l0 = f2bf(xv.x - bf2f(h0)), l1 = f2bf(xv.y - bf2f(h1));
            const int base = AIDX(kf, sq, sb, sj);
            *(short2*)(ahi + base) = make_short2(h0, h1);
            *(short2*)(alo + base) = make_short2(l0, l1);
        }
        __syncthreads();   // barrier A: x (this t) + h (prev t) frags ready

        // ---- load A-fragments ----
        bf16x8 afh[4], afl[4];
        const int abase = AIDX(0, q, r16, 0);
        #pragma unroll
        for (int kf = 0; kf < 4; ++kf) {
            afh[kf] = *(const bf16x8*)(ahi + abase + kf * 512);
            afl[kf] = *(const bf16x8*)(alo + abase + kf * 512);
        }

        // ---- MFMA: preacts for all 4 gates at this wave's d-slice ----
        f32x4 acc[4];
        #pragma unroll
        for (int g = 0; g < 4; ++g)
            acc[g] = (f32x4){biasv[g], biasv[g], biasv[g], biasv[g]};
        #pragma unroll
        for (int kf = 0; kf < 4; ++kf) {
            #pragma unroll
            for (int g = 0; g < 4; ++g) {
                acc[g] = __builtin_amdgcn_mfma_f32_16x16x32_bf16(afh[kf], bhi[g][kf], acc[g], 0, 0, 0);
                acc[g] = __builtin_amdgcn_mfma_f32_16x16x32_bf16(afl[kf], bhi[g][kf], acc[g], 0, 0, 0);
                acc[g] = __builtin_amdgcn_mfma_f32_16x16x32_bf16(afh[kf], blo[g][kf], acc[g], 0, 0, 0);
            }
        }

        // ---- nonlinearity + state update + score partials (C rows 0..7 live in lanes<32) ----
        float sp[4];
        if (lane < 32) {
            const float wtv = wtlds[t * 64 + dcol];
            #pragma unroll
            for (int r = 0; r < 4; ++r) {
                const float ig = sigmoid_f(acc[0][r]);
                const float og = sigmoid_f(acc[1][r]);
                const float fg = sigmoid_f(acc[2][r]);
                const float cg = tanh_f(acc[3][r]);
                const float cn = fmaf(fg, cst[r], ig * cg);
                cst[r] = cn;
                h[r] = og * tanh_f(cn);
                sp[r] = h[r] * wtv;
            }
            // reduce score over this wave's 16 d's (stays within 16-lane group)
            #pragma unroll
            for (int r = 0; r < 4; ++r) {
                #pragma unroll
                for (int mk = 8; mk >= 1; mk >>= 1)
                    sp[r] += __shfl_xor(sp[r], mk, 64);
            }
            if (r16 == 0)
                *(float4*)(sparts + w * 8 + g4) = make_float4(sp[0], sp[1], sp[2], sp[3]);
        }
        __syncthreads();   // barrier B: score partials ready; all A-frag reads done

        if (lane < 32) {
            const int kfh = 2 + (dcol >> 5), kkh = dcol & 31;
            const int qh = kkh >> 3, jh = kkh & 7;
            #pragma unroll
            for (int r = 0; r < 4; ++r) {
                // combine cross-wave score, online softmax
                const float sc = sparts[g4 + r] + sparts[8 + g4 + r] +
                                 sparts[16 + g4 + r] + sparts[24 + g4 + r];
                const float mn = fmaxf(mst[r], sc);
                const float scale = __expf(mst[r] - mn);
                const float p = __expf(sc - mn);
                sst[r]  = fmaf(sst[r], scale, p);
                onum[r] = fmaf(onum[r], scale, p * h[r]);
                mst[r]  = mn;
                // h -> next step's A-frag (hi/lo bf16), safe: all reads done at barrier B
                const short hh = f2bf(h[r]);
                const short hl = f2bf(h[r] - bf2f(hh));
                ahi[AIDX(kfh, qh, g4 + r, jh)] = hh;
                alo[AIDX(kfh, qh, g4 + r, jh)] = hl;
            }
        }
    }

    // ---- output: out[b][n][d] = onum / s ----
    if (lane < 32) {
        #pragma unroll
        for (int r = 0; r < 4; ++r)
            out[((size_t)(g4 + r) * NSTK + n) * 64 + dcol] = onum[r] * rcp_f(sst[r]);
    }
}

extern "C" void kernel_launch(void* const* d_in, const int* in_sizes, int n_in,
                              void* d_out, int out_size, void* d_ws, size_t ws_size,
                              hipStream_t stream) {
    const float* x  = (const float*)d_in[0];
    const float* Wi = (const float*)d_in[1];
    const float* bi = (const float*)d_in[2];
    const float* Wo = (const float*)d_in[3];
    const float* bo = (const float*)d_in[4];
    const float* Wf = (const float*)d_in[5];
    const float* bf = (const float*)d_in[6];
    const float* Wc = (const float*)d_in[7];
    const float* bc = (const float*)d_in[8];
    const float* Wt = (const float*)d_in[9];
    float* out = (float*)d_out;

    lstm_att_mfma<<<NSTK, THREADS, 0, stream>>>(
        x, Wi, bi, Wo, bo, Wf, bf, Wc, bc, Wt, out);
}

// Round 4
// 63.459 us; speedup vs baseline: 1.8780x; 1.8780x over previous
//
#include <hip/hip_runtime.h>

#define TT 20
#define NSTK 1000
#define THREADS 256

typedef float f32x4 __attribute__((ext_vector_type(4)));
typedef _Float16 f16x8 __attribute__((ext_vector_type(8)));
typedef _Float16 f16x2 __attribute__((ext_vector_type(2)));

__device__ __forceinline__ float rcp_f(float x) { return __builtin_amdgcn_rcpf(x); }
__device__ __forceinline__ float sigmoid_f(float x) { return rcp_f(1.0f + __expf(-x)); }
__device__ __forceinline__ float tanh_f(float x) {
    return 1.0f - 2.0f * rcp_f(__expf(2.0f * x) + 1.0f);
}

// A/B fragment k-convention: k = kf*32 + q*8 + j  (q = lane>>4, j = elem).
// Same bijection used for A and B, so the true HW k-permutation cancels.
// A-frag LDS layout: [kf][q][row][j], shorts.
#define AIDX(kf, q, row, j) ((((kf) * 4 + (q)) * 16 + (row)) * 8 + (j))

extern "C" __global__ void __launch_bounds__(THREADS, 3)
lstm_att_f16(const float* __restrict__ x,
             const float* __restrict__ Wi, const float* __restrict__ bi,
             const float* __restrict__ Wo, const float* __restrict__ bo,
             const float* __restrict__ Wf, const float* __restrict__ bf_,
             const float* __restrict__ Wc, const float* __restrict__ bc,
             const float* __restrict__ Wt,
             float* __restrict__ out)
{
    __shared__ __align__(16) _Float16 afrag[2048];        // 4 KB  xh fragments (f16)
    __shared__ __align__(16) _Float16 hhist[TT * 8 * 64]; // 20 KB h history
    __shared__ __align__(16) float    wtlds[TT * 64];     // 5 KB

    const int n    = blockIdx.x;
    const int tid  = threadIdx.x;
    const int lane = tid & 63;
    const int w    = tid >> 6;            // wave 0..3
    const int q    = lane >> 4;           // k-subgroup
    const int r16  = lane & 15;           // A row / B col within frag
    const int dcol = w * 16 + r16;        // this lane's d column (0..63)
    const int g4   = q * 4;               // batch base of C rows (lanes<32)

    // ---- persistent weight B-frags, direct global->reg (read-once, 64B-segment efficient) ----
    f16x8 bw[4][4];                       // [gate][kf] = 64 VGPRs
    {
        const float* Wg[4] = {Wi, Wo, Wf, Wc};
        #pragma unroll
        for (int g = 0; g < 4; ++g) {
            const float* base = Wg[g] + (size_t)n * 8192 + dcol;
            #pragma unroll
            for (int kf = 0; kf < 4; ++kf)
                #pragma unroll
                for (int j = 0; j < 8; ++j)
                    bw[g][kf][j] = (_Float16)base[(kf * 32 + q * 8 + j) * 64];
        }
    }
    float biasv[4];
    biasv[0] = bi[n * 64 + dcol];
    biasv[1] = bo[n * 64 + dcol];
    biasv[2] = bf_[n * 64 + dcol];
    biasv[3] = bc[n * 64 + dcol];

    // ---- init LDS: Wt, zero h-slots of afrag ----
    #pragma unroll
    for (int u = 0; u < 5; ++u)
        wtlds[tid + u * THREADS] = Wt[(size_t)n * (TT * 64) + tid + u * THREADS];
    #pragma unroll
    for (int u = 0; u < 4; ++u)
        afrag[1024 + tid + u * THREADS] = (_Float16)0.0f;   // kf=2,3 (h part, k in [64,128))

    // ---- x staging role: thread -> (batch sb, dims dx, dx+1); prefetch t=0 ----
    const int sb = tid >> 5, dx = (tid & 31) * 2;
    const int skf = dx >> 5, skk = dx & 31;
    const int sbase = AIDX(skf, skk >> 3, sb, skk & 7);     // dx even -> j, j+1 in same frag
    const float* xptr = x + ((size_t)sb * TT * NSTK + (size_t)n) * 64 + dx;
    float2 xreg = *(const float2*)xptr;

    float cst[4] = {0.f, 0.f, 0.f, 0.f};
    float hv[4];

    __syncthreads();    // zeroed h-slots visible

    for (int t = 0; t < TT; ++t) {
        // stage prefetched x into frag layout; issue next prefetch (hidden under MFMA+epilogue)
        *(f16x2*)(afrag + sbase) = (f16x2){(_Float16)xreg.x, (_Float16)xreg.y};
        const int tn = (t + 1 < TT) ? t + 1 : t;
        xreg = *(const float2*)(xptr + (size_t)tn * NSTK * 64);
        __syncthreads();    // barrier A: x (this t) + h (prev t) ready

        f16x8 af[4];
        #pragma unroll
        for (int kf = 0; kf < 4; ++kf)
            af[kf] = *(const f16x8*)(afrag + AIDX(kf, q, r16, 0));

        f32x4 acc[4];
        #pragma unroll
        for (int g = 0; g < 4; ++g)
            acc[g] = (f32x4){biasv[g], biasv[g], biasv[g], biasv[g]};
        #pragma unroll
        for (int kf = 0; kf < 4; ++kf) {
            #pragma unroll
            for (int g = 0; g < 4; ++g)
                acc[g] = __builtin_amdgcn_mfma_f32_16x16x32_f16(af[kf], bw[g][kf], acc[g], 0, 0, 0);
        }

        // gates + state update (C rows 0..7 live in lanes<32: row = q*4 + reg)
        if (lane < 32) {
            #pragma unroll
            for (int r = 0; r < 4; ++r) {
                const float ig = sigmoid_f(acc[0][r]);
                const float og = sigmoid_f(acc[1][r]);
                const float fg = sigmoid_f(acc[2][r]);
                const float cg = tanh_f(acc[3][r]);
                const float cn = fmaf(fg, cst[r], ig * cg);
                cst[r] = cn;
                hv[r] = og * tanh_f(cn);
                hhist[(t * 8 + g4 + r) * 64 + dcol] = (_Float16)hv[r];
            }
        }
        __syncthreads();    // barrier B: all A-frag reads of step t complete

        if (lane < 32) {
            const int kfh = 2 + (dcol >> 5), kkh = dcol & 31;
            const int hb = AIDX(kfh, kkh >> 3, 0, kkh & 7);
            #pragma unroll
            for (int r = 0; r < 4; ++r)
                afrag[hb + (g4 + r) * 8] = (_Float16)hv[r];   // h -> next step's A-frag
        }
    }

    __syncthreads();    // hhist complete

    // ---- deferred attention: wave w handles batches 2w, 2w+1 ----
    #pragma unroll
    for (int bb = 0; bb < 2; ++bb) {
        const int b = 2 * w + bb;
        float s[TT];
        #pragma unroll
        for (int t = 0; t < TT; ++t)
            s[t] = (float)hhist[(t * 8 + b) * 64 + lane] * wtlds[t * 64 + lane];
        #pragma unroll
        for (int t = 0; t < TT; ++t) {
            #pragma unroll
            for (int mk = 32; mk >= 1; mk >>= 1)
                s[t] += __shfl_xor(s[t], mk, 64);
        }
        float m = s[0];
        #pragma unroll
        for (int t = 1; t < TT; ++t) m = fmaxf(m, s[t]);
        float se = 0.f;
        #pragma unroll
        for (int t = 0; t < TT; ++t) { s[t] = __expf(s[t] - m); se += s[t]; }
        const float rs = rcp_f(se);
        float o = 0.f;
        #pragma unroll
        for (int t = 0; t < TT; ++t)
            o = fmaf(s[t], (float)hhist[(t * 8 + b) * 64 + lane], o);
        out[((size_t)b * NSTK + n) * 64 + lane] = o * rs;
    }
}

extern "C" void kernel_launch(void* const* d_in, const int* in_sizes, int n_in,
                              void* d_out, int out_size, void* d_ws, size_t ws_size,
                              hipStream_t stream) {
    const float* x  = (const float*)d_in[0];
    const float* Wi = (const float*)d_in[1];
    const float* bi = (const float*)d_in[2];
    const float* Wo = (const float*)d_in[3];
    const float* bo = (const float*)d_in[4];
    const float* Wf = (const float*)d_in[5];
    const float* bf = (const float*)d_in[6];
    const float* Wc = (const float*)d_in[7];
    const float* bc = (const float*)d_in[8];
    const float* Wt = (const float*)d_in[9];
    float* out = (float*)d_out;

    lstm_att_f16<<<NSTK, THREADS, 0, stream>>>(
        x, Wi, bi, Wo, bo, Wf, bf, Wc, bc, Wt, out);
}

// Round 5
// 56.915 us; speedup vs baseline: 2.0939x; 1.1150x over previous
//
#include <hip/hip_runtime.h>

#define TT 20
#define NSTK 1000
#define THREADS 256

typedef float f32x4 __attribute__((ext_vector_type(4)));
typedef _Float16 f16x8 __attribute__((ext_vector_type(8)));
typedef _Float16 f16x2 __attribute__((ext_vector_type(2)));

__device__ __forceinline__ float rcp_f(float x) { return __builtin_amdgcn_rcpf(x); }
__device__ __forceinline__ float sigmoid_f(float x) { return rcp_f(1.0f + __expf(-x)); }
__device__ __forceinline__ float tanh_f(float x) {
    return 1.0f - 2.0f * rcp_f(__expf(2.0f * x) + 1.0f);
}

// A/B fragment k-convention: k = kf*32 + q*8 + j  (q = lane>>4, j = elem).
// Same bijection for A and B, so the true HW k-permutation cancels.
// A-frag LDS layout: [kf][q][row][j] shorts. kf 0,1 = x rows; kf 2,3 = h rows.
// Rows 8..15 are never written/zeroed: they only feed C rows 8..15, which are discarded.
#define AIDX(kf, q, row, j) ((((kf) * 4 + (q)) * 16 + (row)) * 8 + (j))

extern "C" __global__ void __launch_bounds__(THREADS, 4)
lstm_att_f16(const float* __restrict__ x,
             const float* __restrict__ Wi, const float* __restrict__ bi,
             const float* __restrict__ Wo, const float* __restrict__ bo,
             const float* __restrict__ Wf, const float* __restrict__ bf_,
             const float* __restrict__ Wc, const float* __restrict__ bc,
             const float* __restrict__ Wt,
             float* __restrict__ out)
{
    __shared__ __align__(16) _Float16 afrag[2][2048];     // 8 KB  xh frags, double-buffered
    __shared__ __align__(16) _Float16 hhist[TT * 8 * 64]; // 20 KB h history

    const int n    = blockIdx.x;
    const int tid  = threadIdx.x;
    const int lane = tid & 63;
    const int w    = tid >> 6;            // wave 0..3
    const int q    = lane >> 4;           // k-subgroup
    const int r16  = lane & 15;           // A row / B col within frag
    const int dcol = w * 16 + r16;        // this lane's d column (0..63)
    const bool hi  = lane >= 32;
    const int rowbase = ((lane & 31) >> 4) * 4 + (hi ? 2 : 0);  // this lane's 2 batch rows

    // ---- persistent weight B-frags, direct global->reg ----
    f16x8 bw[4][4];                       // [gate][kf]
    {
        const float* Wg[4] = {Wi, Wo, Wf, Wc};
        #pragma unroll
        for (int g = 0; g < 4; ++g) {
            const float* base = Wg[g] + (size_t)n * 8192 + dcol;
            #pragma unroll
            for (int kf = 0; kf < 4; ++kf)
                #pragma unroll
                for (int j = 0; j < 8; ++j)
                    bw[g][kf][j] = (_Float16)base[(kf * 32 + q * 8 + j) * 64];
        }
    }
    float biasv[4];
    biasv[0] = bi[n * 64 + dcol];
    biasv[1] = bo[n * 64 + dcol];
    biasv[2] = bf_[n * 64 + dcol];
    biasv[3] = bc[n * 64 + dcol];

    // ---- x staging role: thread -> (batch sb, dims dx,dx+1) ----
    const int sb = tid >> 5, dx = (tid & 31) * 2;
    const int sbase = AIDX(dx >> 5, (dx & 31) >> 3, sb, dx & 7);  // dx even -> j,j+1 same frag
    const float* xptr = x + ((size_t)sb * TT * NSTK + (size_t)n) * 64 + dx;

    // init: stage x(t=0) into buf0; zero h rows of buf0
    {
        const float2 x0 = *(const float2*)xptr;
        *(f16x2*)(&afrag[0][sbase]) = (f16x2){(_Float16)x0.x, (_Float16)x0.y};
        #pragma unroll
        for (int u = 0; u < 4; ++u)
            afrag[0][1024 + tid + u * THREADS] = (_Float16)0.0f;
    }
    float2 xreg = *(const float2*)(xptr + (size_t)NSTK * 64);   // prefetch t=1

    float cst0 = 0.f, cst1 = 0.f;        // cell state for rows rowbase, rowbase+1

    __syncthreads();

    const int kfh = 2 + (dcol >> 5), kkh = dcol & 31;
    const int hb0 = AIDX(kfh, kkh >> 3, rowbase, kkh & 7);      // h slot, row rowbase

    for (int t = 0; t < TT; ++t) {
        const int cur = t & 1, nxt = cur ^ 1;

        // A-frag reads from current buffer
        f16x8 af[4];
        #pragma unroll
        for (int kf = 0; kf < 4; ++kf)
            af[kf] = *(const f16x8*)(&afrag[cur][AIDX(kf, q, r16, 0)]);

        // stage x(t+1) into next buffer (different buffer: no hazard vs reads above)
        if (t + 1 < TT)
            *(f16x2*)(&afrag[nxt][sbase]) = (f16x2){(_Float16)xreg.x, (_Float16)xreg.y};
        {
            const int tn = (t + 2 < TT) ? t + 2 : TT - 1;
            xreg = *(const float2*)(xptr + (size_t)tn * NSTK * 64);  // hidden under MFMA
        }

        f32x4 acc[4];
        #pragma unroll
        for (int g = 0; g < 4; ++g)
            acc[g] = (f32x4){biasv[g], biasv[g], biasv[g], biasv[g]};
        #pragma unroll
        for (int kf = 0; kf < 4; ++kf) {
            #pragma unroll
            for (int g = 0; g < 4; ++g)
                acc[g] = __builtin_amdgcn_mfma_f32_16x16x32_f16(af[kf], bw[g][kf], acc[g], 0, 0, 0);
        }

        // ship C rows 2,3 to partner lane (+32); every lane then handles 2 rows
        float p0[4], p1[4];
        #pragma unroll
        for (int g = 0; g < 4; ++g) {
            const float t2 = __shfl_xor(acc[g][2], 32, 64);
            const float t3 = __shfl_xor(acc[g][3], 32, 64);
            p0[g] = hi ? t2 : acc[g][0];
            p1[g] = hi ? t3 : acc[g][1];
        }

        const float ig0 = sigmoid_f(p0[0]), og0 = sigmoid_f(p0[1]);
        const float fg0 = sigmoid_f(p0[2]), cg0 = tanh_f(p0[3]);
        const float ig1 = sigmoid_f(p1[0]), og1 = sigmoid_f(p1[1]);
        const float fg1 = sigmoid_f(p1[2]), cg1 = tanh_f(p1[3]);
        cst0 = fmaf(fg0, cst0, ig0 * cg0);
        cst1 = fmaf(fg1, cst1, ig1 * cg1);
        const float h0 = og0 * tanh_f(cst0);
        const float h1 = og1 * tanh_f(cst1);

        // h -> next buffer's A-frag + history
        afrag[nxt][hb0]     = (_Float16)h0;
        afrag[nxt][hb0 + 8] = (_Float16)h1;          // row+1 => +8 shorts
        hhist[(t * 8 + rowbase) * 64 + dcol]     = (_Float16)h0;
        hhist[(t * 8 + rowbase + 1) * 64 + dcol] = (_Float16)h1;

        __syncthreads();   // single barrier: publishes x(t+1)+h(t) in buf[nxt]; closes reads of buf[cur]
    }

    // ---- deferred attention: wave w handles batches 2w, 2w+1 (hhist ready after last barrier) ----
    const float* wtg = Wt + (size_t)n * (TT * 64);
    #pragma unroll
    for (int bb = 0; bb < 2; ++bb) {
        const int b = 2 * w + bb;
        float s[TT];
        #pragma unroll
        for (int t = 0; t < TT; ++t)
            s[t] = (float)hhist[(t * 8 + b) * 64 + lane] * wtg[t * 64 + lane];
        #pragma unroll
        for (int t = 0; t < TT; ++t) {
            #pragma unroll
            for (int mk = 32; mk >= 1; mk >>= 1)
                s[t] += __shfl_xor(s[t], mk, 64);
        }
        float m = s[0];
        #pragma unroll
        for (int t = 1; t < TT; ++t) m = fmaxf(m, s[t]);
        float se = 0.f;
        #pragma unroll
        for (int t = 0; t < TT; ++t) { s[t] = __expf(s[t] - m); se += s[t]; }
        const float rs = rcp_f(se);
        float o = 0.f;
        #pragma unroll
        for (int t = 0; t < TT; ++t)
            o = fmaf(s[t], (float)hhist[(t * 8 + b) * 64 + lane], o);
        out[((size_t)b * NSTK + n) * 64 + lane] = o * rs;
    }
}

extern "C" void kernel_launch(void* const* d_in, const int* in_sizes, int n_in,
                              void* d_out, int out_size, void* d_ws, size_t ws_size,
                              hipStream_t stream) {
    const float* x  = (const float*)d_in[0];
    const float* Wi = (const float*)d_in[1];
    const float* bi = (const float*)d_in[2];
    const float* Wo = (const float*)d_in[3];
    const float* bo = (const float*)d_in[4];
    const float* Wf = (const float*)d_in[5];
    const float* bf = (const float*)d_in[6];
    const float* Wc = (const float*)d_in[7];
    const float* bc = (const float*)d_in[8];
    const float* Wt = (const float*)d_in[9];
    float* out = (float*)d_out;

    lstm_att_f16<<<NSTK, THREADS, 0, stream>>>(
        x, Wi, bi, Wo, bo, Wf, bf, Wc, bc, Wt, out);
}